// Round 20
// baseline (493.423 us; speedup 1.0000x reference)
//
#include <hip/hip_runtime.h>
#include <math.h>

#define N_NODES 100000
#define N_EDGES 3200000
#define F_IN    512
#define HIDDEN  256
#define NCLASS  40
#define NPAD    48
#define H2STRIDE 64
#define FB_ROWS 16
#define G1_BLOCKS ((N_NODES + 127) / 128)        // 782
#define FILLB     1563                           // fill blocks (grid-stride x4)
#define FILLSTRIDE (FILLB * 512)                 // 800256

#define SCAN_B  256
#define N_SCANB ((N_NODES + SCAN_B - 1) / SCAN_B)   // 391

typedef __attribute__((ext_vector_type(8))) _Float16 half8;
typedef __attribute__((ext_vector_type(4))) _Float16 half4;
typedef __attribute__((ext_vector_type(4))) float    f32x4;
typedef __attribute__((ext_vector_type(2))) float    f32x2;

__device__ __forceinline__ float unpack_val(unsigned pk) {
    unsigned short hb = (unsigned short)(pk & 0x7FFFu);
    _Float16 h = *(_Float16*)&hb;
    return (float)h;
}

// ---------------------------------------------------------------------------
// init: deg = 0  +  W1 -> W1T [256][512] fp16  +  W2 -> W2T [48][256] fp16
// ---------------------------------------------------------------------------
__global__ __launch_bounds__(256) void init_kernel(const float* __restrict__ W1,
                                                   const float* __restrict__ W2,
                                                   _Float16* __restrict__ W1T,
                                                   _Float16* __restrict__ W2T,
                                                   int* __restrict__ deg) {
    int o = blockIdx.x * 256 + threadIdx.x;   // 0..131071
    {
        int n = o >> 9, k = o & 511;
        W1T[o] = (_Float16)W1[(size_t)k * HIDDEN + n];
    }
    if (o < NPAD * HIDDEN) {                  // 0..12287
        int n = o >> 8, k = o & 255;
        W2T[o] = (n < NCLASS) ? (_Float16)W2[(size_t)k * NCLASS + n] : (_Float16)0.f;
    }
    if (o < N_NODES) deg[o] = 0;
}

// ---------------------------------------------------------------------------
// CSR build: pass 1 = histogram + per-edge rank (atomic return value)
// ---------------------------------------------------------------------------
__global__ __launch_bounds__(256) void hist2_kernel(const int* __restrict__ erow,
                                                    int* __restrict__ deg,
                                                    unsigned short* __restrict__ ke, int E) {
    int e = blockIdx.x * 256 + threadIdx.x;
    if (e < E) ke[e] = (unsigned short)atomicAdd(&deg[erow[e]], 1);
}

__global__ __launch_bounds__(256) void scanA_kernel(const int* __restrict__ deg,
                                                    int* __restrict__ rptr,
                                                    int* __restrict__ bsum, int n) {
    __shared__ int s[SCAN_B];
    int i = blockIdx.x * SCAN_B + threadIdx.x;
    int v = (i < n) ? deg[i] : 0;
    s[threadIdx.x] = v;
    __syncthreads();
    #pragma unroll
    for (int off = 1; off < SCAN_B; off <<= 1) {
        int t = (threadIdx.x >= off) ? s[threadIdx.x - off] : 0;
        __syncthreads();
        s[threadIdx.x] += t;
        __syncthreads();
    }
    if (i < n) rptr[i] = s[threadIdx.x] - v;
    if (threadIdx.x == SCAN_B - 1) bsum[blockIdx.x] = s[SCAN_B - 1];
}

__global__ __launch_bounds__(512) void scanB_kernel(int* __restrict__ bsum, int nb) {
    __shared__ int s[512];
    int t = threadIdx.x;
    int v = (t < nb) ? bsum[t] : 0;
    s[t] = v;
    __syncthreads();
    #pragma unroll
    for (int off = 1; off < 512; off <<= 1) {
        int x = (t >= off) ? s[t - off] : 0;
        __syncthreads();
        s[t] += x;
        __syncthreads();
    }
    if (t < nb) bsum[t] = s[t] - v;
}

__global__ __launch_bounds__(256) void scanC_kernel(int* __restrict__ rptr,
                                                    const int* __restrict__ bsum,
                                                    int n, int E) {
    int i = blockIdx.x * SCAN_B + threadIdx.x;
    if (i < n) rptr[i] += bsum[blockIdx.x];
    if (i == 0) rptr[n] = E;
}

// ---------------------------------------------------------------------------
// MERGED (512 threads): blocks [0, G1_BLOCKS) = GEMM1 ; rest = fill.
// GEMM1: 128x256 tile, 8 waves each with a 64x64 wave tile. (R18-proven)
// fill: grid-stride x4 (4 independent edge chains per thread).
// ---------------------------------------------------------------------------
__global__ __launch_bounds__(512) void fill_gemm1_kernel(
        const float* __restrict__ A, const _Float16* __restrict__ BT,
        unsigned char* __restrict__ C, int M,
        const int* __restrict__ erow, const int* __restrict__ ecol,
        const float* __restrict__ evals, const int* __restrict__ rptr,
        const unsigned short* __restrict__ ke, unsigned* __restrict__ cvp, int E) {
    __shared__ __align__(16) char smem[30720];

    if (blockIdx.x >= G1_BLOCKS) {
        // ---- fill: permute packed (col,val) -> CSR slots, no atomics ----
        int base = (blockIdx.x - G1_BLOCKS) * 512 + threadIdx.x;
        #pragma unroll
        for (int i = 0; i < 4; i++) {
            int e = base + i * FILLSTRIDE;
            if (e < E) {
                int p = rptr[erow[e]] + ke[e];
                _Float16 h = (_Float16)evals[e];
                unsigned short hb = *(unsigned short*)&h;
                cvp[p] = ((unsigned)ecol[e] << 15) | (unsigned)(hb & 0x7FFFu);
            }
        }
        return;
    }

    _Float16 (*As)[40]  = (_Float16 (*)[40])smem;               // 128x40 = 10240 B
    _Float16 (*Bs)[40]  = (_Float16 (*)[40])(smem + 10240);     // 256x40 = 20480 B
    _Float16 (*sC)[264] = (_Float16 (*)[264])smem;              //  32x264 = 16896 B (aliases)

    const int t    = threadIdx.x;       // 0..511
    const int m0   = blockIdx.x * 128;
    const int lane = t & 63;
    const int wid  = t >> 6;            // 0..7
    const int wm   = wid >> 2;          // 0..1 (64-row half)
    const int wn   = wid & 3;           // 0..3 (64-col quarter)
    const int lr   = lane & 15, lk = lane >> 4;

    f32x4 acc[4][4] = {};

    const int  ar   = t >> 2;           // 0..127
    const int  aq   = t & 3;            // 0..3 (8-float chunk)
    const bool aval = (m0 + ar) < M;
    const float*    aptr = A  + (size_t)(m0 + ar) * F_IN + aq * 8;
    const _Float16* bptr = BT + (size_t)(t >> 1) * F_IN + (t & 1) * 16;

    float4 a0 = {0.f,0.f,0.f,0.f}, a1 = {0.f,0.f,0.f,0.f};
    half8 b0, b1;
    if (aval) { a0 = *(const float4*)(aptr); a1 = *(const float4*)(aptr + 4); }
    { const half8* bp = (const half8*)(bptr); b0 = bp[0]; b1 = bp[1]; }

    for (int k0 = 0; k0 < F_IN; k0 += 32) {
        half8 ah;
        ah[0]=(_Float16)a0.x; ah[1]=(_Float16)a0.y; ah[2]=(_Float16)a0.z; ah[3]=(_Float16)a0.w;
        ah[4]=(_Float16)a1.x; ah[5]=(_Float16)a1.y; ah[6]=(_Float16)a1.z; ah[7]=(_Float16)a1.w;
        *(half8*)&As[ar][aq * 8] = ah;
        *(half8*)&Bs[t >> 1][(t & 1) * 16]     = b0;
        *(half8*)&Bs[t >> 1][(t & 1) * 16 + 8] = b1;
        __syncthreads();

        if (k0 + 32 < F_IN) {
            if (aval) {
                a0 = *(const float4*)(aptr + k0 + 32);
                a1 = *(const float4*)(aptr + k0 + 36);
            }
            const half8* bp = (const half8*)(bptr + k0 + 32);
            b0 = bp[0]; b1 = bp[1];
        }

        half8 af[4], bf[4];
        #pragma unroll
        for (int fm = 0; fm < 4; fm++) af[fm] = *(half8*)&As[wm * 64 + fm * 16 + lr][lk * 8];
        #pragma unroll
        for (int fn = 0; fn < 4; fn++) bf[fn] = *(half8*)&Bs[wn * 64 + fn * 16 + lr][lk * 8];
        #pragma unroll
        for (int fm = 0; fm < 4; fm++)
            #pragma unroll
            for (int fn = 0; fn < 4; fn++)
                acc[fm][fn] = __builtin_amdgcn_mfma_f32_16x16x32_f16(af[fm], bf[fn], acc[fm][fn], 0, 0, 0);
        __syncthreads();
    }

    // epilogue: four 32-row passes; pass p covers rows [32p, 32p+32)
    #pragma unroll
    for (int pass = 0; pass < 4; pass++) {
        if (wm == (pass >> 1)) {
            #pragma unroll
            for (int f2 = 0; f2 < 2; f2++) {
                int fm = (pass & 1) * 2 + f2;
                #pragma unroll
                for (int fn = 0; fn < 4; fn++)
                    #pragma unroll
                    for (int j = 0; j < 4; j++) {
                        int row = f2 * 16 + lk * 4 + j;        // 0..31
                        int col = wn * 64 + fn * 16 + lr;
                        sC[row][col] = (_Float16)acc[fm][fn][j];
                    }
            }
        }
        __syncthreads();

        int row = t >> 4;          // 0..31
        int c   = t & 15;          // 0..15 (16 fp8 chunk)
        int m   = m0 + pass * 32 + row;
        if (m < M) {
            const half8* sp = (const half8*)&sC[row][c * 16];
            half8 h0 = sp[0], h1 = sp[1];
            unsigned w0 = __builtin_amdgcn_cvt_pk_fp8_f32((float)h0[0], (float)h0[1], 0u, false);
            w0 = __builtin_amdgcn_cvt_pk_fp8_f32((float)h0[2], (float)h0[3], w0, true);
            unsigned w1 = __builtin_amdgcn_cvt_pk_fp8_f32((float)h0[4], (float)h0[5], 0u, false);
            w1 = __builtin_amdgcn_cvt_pk_fp8_f32((float)h0[6], (float)h0[7], w1, true);
            unsigned w2 = __builtin_amdgcn_cvt_pk_fp8_f32((float)h1[0], (float)h1[1], 0u, false);
            w2 = __builtin_amdgcn_cvt_pk_fp8_f32((float)h1[2], (float)h1[3], w2, true);
            unsigned w3 = __builtin_amdgcn_cvt_pk_fp8_f32((float)h1[4], (float)h1[5], 0u, false);
            w3 = __builtin_amdgcn_cvt_pk_fp8_f32((float)h1[6], (float)h1[7], w3, true);
            *(uint4*)(C + (size_t)m * HIDDEN + c * 16) = make_uint4(w0, w1, w2, w3);
        }
        __syncthreads();
    }
}

// ---------------------------------------------------------------------------
// FUSED: SpMM gather D=256 (fp8 table) + ReLU + GEMM2 (@W2 via MFMA epilogue).
// 1024 threads = 16 waves = 16 rows. 24 edges/iter (6 gathers in flight),
// pk block prefetched one iteration ahead.
// ---------------------------------------------------------------------------
__global__ __launch_bounds__(1024) void spmm_gemm2_kernel(const int* __restrict__ rptr,
                                                          const unsigned* __restrict__ cvp,
                                                          const unsigned char* __restrict__ H1,
                                                          const _Float16* __restrict__ W2T,
                                                          _Float16* __restrict__ H2) {
    __shared__ _Float16 sW2[NPAD][264];     // 25344 B
    __shared__ _Float16 sRow[16][264];      //  8448 B

    int t = threadIdx.x;
    int wave = t >> 6, lane = t & 63;
    int m0 = blockIdx.x * FB_ROWS;
    int r = m0 + wave;

    // stage W2T (48x256 = 1536 half8 chunks) : 1.5 per thread
    #pragma unroll
    for (int i = 0; i < 2; i++) {
        int idx = t + i * 1024;             // 0..2047
        if (idx < NPAD * 32) {
            int row = idx >> 5, c8 = idx & 31;
            *(half8*)&sW2[row][c8 * 8] = *(const half8*)(W2T + (size_t)row * HIDDEN + c8 * 8);
        }
    }

    int e0 = rptr[r], e1 = rptr[r + 1];
    int qf = lane >> 4;            // which edge of the quad (0..3)
    int fl = lane & 15;            // 16B feature block (16 fp8 each)

    float acc[16] = {};
    unsigned pkb[6];
    if (e0 < e1) {
        #pragma unroll
        for (int u = 0; u < 6; u++) {
            int idx = e0 + 4 * u + qf;
            pkb[u] = cvp[idx < e1 ? idx : (e1 - 1)];
        }
    }
    for (int e = e0; e < e1; e += 24) {
        unsigned pkc[6];
        #pragma unroll
        for (int u = 0; u < 6; u++) pkc[u] = pkb[u];
        // prefetch next iteration's pk block (overlaps with gathers below)
        if (e + 24 < e1) {
            #pragma unroll
            for (int u = 0; u < 6; u++) {
                int idx = e + 24 + 4 * u + qf;
                pkb[u] = cvp[idx < e1 ? idx : (e1 - 1)];
            }
        }
        #pragma unroll
        for (int u = 0; u < 6; u++) {
            int idx = e + 4 * u + qf;
            bool ok = idx < e1;
            unsigned pk = pkc[u];
            float v = ok ? unpack_val(pk) : 0.f;
            int col = (int)(pk >> 15);
            uint4 raw = *(const uint4*)(H1 + (size_t)col * HIDDEN + fl * 16);
            #pragma unroll
            for (int q = 0; q < 4; q++) {
                unsigned wq = (q == 0) ? raw.x : (q == 1) ? raw.y : (q == 2) ? raw.z : raw.w;
                f32x2 lo = __builtin_amdgcn_cvt_pk_f32_fp8(wq, false);
                f32x2 hi = __builtin_amdgcn_cvt_pk_f32_fp8(wq, true);
                acc[q*4 + 0] += v * lo[0];
                acc[q*4 + 1] += v * lo[1];
                acc[q*4 + 2] += v * hi[0];
                acc[q*4 + 3] += v * hi[1];
            }
        }
    }
    // merge the 4 quad groups: lanes 0..15 end with the full sums
    #pragma unroll
    for (int j = 0; j < 16; j++) {
        acc[j] += __shfl_xor(acc[j], 32);
        acc[j] += __shfl_xor(acc[j], 16);
    }

    if (lane < 16) {
        half8 o0, o1;
        #pragma unroll
        for (int j = 0; j < 8; j++) {
            o0[j] = (_Float16)fmaxf(acc[j], 0.f);
            o1[j] = (_Float16)fmaxf(acc[8 + j], 0.f);
        }
        *(half8*)&sRow[wave][fl * 16]     = o0;
        *(half8*)&sRow[wave][fl * 16 + 8] = o1;
    }
    __syncthreads();

    // MFMA epilogue on wave 0: [16x256] @ [48x256]^T
    if (wave == 0) {
        int lr = lane & 15, lk = lane >> 4;
        f32x4 acc2[3] = {};
        #pragma unroll
        for (int ks = 0; ks < 8; ks++) {
            half8 af = *(half8*)&sRow[lr][ks * 32 + lk * 8];
            #pragma unroll
            for (int fn = 0; fn < 3; fn++) {
                half8 bf = *(half8*)&sW2[fn * 16 + lr][ks * 32 + lk * 8];
                acc2[fn] = __builtin_amdgcn_mfma_f32_16x16x32_f16(af, bf, acc2[fn], 0, 0, 0);
            }
        }
        #pragma unroll
        for (int fn = 0; fn < 3; fn++)
            #pragma unroll
            for (int j = 0; j < 4; j++) {
                int row = lk * 4 + j;       // 0..15
                int col = fn * 16 + lr;     // 0..47
                H2[(size_t)(m0 + row) * H2STRIDE + col] = (_Float16)acc2[fn][j];
            }
    }
}

// ---------------------------------------------------------------------------
// SpMM gather D=40 (fp16, stride-64 rows) + ReLU + log_softmax.
// One wave per row; 48 edges/iter (4 independent gathers), pk prefetched.
// ---------------------------------------------------------------------------
__global__ __launch_bounds__(256) void spmm40_ls_kernel(const int* __restrict__ rptr,
                                                        const unsigned* __restrict__ cvp,
                                                        const _Float16* __restrict__ H2,
                                                        float* __restrict__ out) {
    int t = threadIdx.x;
    int wave = t >> 6, lane = t & 63;
    int r = blockIdx.x * 4 + wave;

    int e0 = rptr[r], e1 = rptr[r + 1];
    int s = lane / 5;           // edge slot 0..11 (lane 60..63 inactive)
    int g = lane % 5;           // feature block: classes g*8 .. g*8+7
    bool lact = lane < 60;

    float acc[8] = {};
    unsigned pb[4];
    if (e0 < e1) {
        #pragma unroll
        for (int j = 0; j < 4; j++) {
            int ij = e0 + j * 12 + s;
            pb[j] = cvp[(lact && ij < e1) ? ij : (e1 - 1)];
        }
    }
    for (int e = e0; e < e1; e += 48) {
        unsigned pc[4];
        #pragma unroll
        for (int j = 0; j < 4; j++) pc[j] = pb[j];
        int en = e + 48;
        if (en < e1) {
            #pragma unroll
            for (int j = 0; j < 4; j++) {
                int ij = en + j * 12 + s;
                pb[j] = cvp[(lact && ij < e1) ? ij : (e1 - 1)];
            }
        }
        #pragma unroll
        for (int j = 0; j < 4; j++) {
            bool ok = lact && (e + j * 12 + s < e1);
            float v = ok ? unpack_val(pc[j]) : 0.f;
            int c = (int)(pc[j] >> 15);
            half8 h = *(const half8*)(H2 + (size_t)c * H2STRIDE + g * 8);
            #pragma unroll
            for (int k = 0; k < 8; k++)
                acc[k] += v * (float)h[k];
        }
    }

    // slot-tree reduce: 12 -> 6 -> 3 -> 1
    #pragma unroll
    for (int j = 0; j < 8; j++) acc[j] += __shfl(acc[j], lane + 30);
    #pragma unroll
    for (int j = 0; j < 8; j++) acc[j] += __shfl(acc[j], lane + 15);
    #pragma unroll
    for (int j = 0; j < 8; j++) {
        float t1 = __shfl(acc[j], lane + 5);
        float t2 = __shfl(acc[j], lane + 10);
        acc[j] += t1 + t2;
    }

    bool act = lane < 5;
    float z[8];
    float mx = -INFINITY;
    #pragma unroll
    for (int j = 0; j < 8; j++) {
        z[j] = act ? fmaxf(acc[j], 0.f) : -INFINITY;
        mx = fmaxf(mx, z[j]);
    }
    mx = fmaxf(mx, __shfl_xor(mx, 1));
    mx = fmaxf(mx, __shfl_xor(mx, 2));
    mx = fmaxf(mx, __shfl_xor(mx, 4));

    float sm = 0.f;
    #pragma unroll
    for (int j = 0; j < 8; j++)
        sm += act ? expf(z[j] - mx) : 0.f;
    sm += __shfl_xor(sm, 1);
    sm += __shfl_xor(sm, 2);
    sm += __shfl_xor(sm, 4);

    float lse = logf(sm);
    if (act) {
        float4 o0 = {z[0]-mx-lse, z[1]-mx-lse, z[2]-mx-lse, z[3]-mx-lse};
        float4 o1 = {z[4]-mx-lse, z[5]-mx-lse, z[6]-mx-lse, z[7]-mx-lse};
        float4* dp = (float4*)(out + (size_t)r * NCLASS + g * 8);
        dp[0] = o0;
        dp[1] = o1;
    }
}

// ---------------------------------------------------------------------------
extern "C" void kernel_launch(void* const* d_in, const int* in_sizes, int n_in,
                              void* d_out, int out_size, void* d_ws, size_t ws_size,
                              hipStream_t stream) {
    const float* x     = (const float*)d_in[0];
    const int*   erow  = (const int*)d_in[1];
    const int*   ecol  = (const int*)d_in[2];
    const float* evals = (const float*)d_in[3];
    const float* W1    = (const float*)d_in[4];
    const float* W2    = (const float*)d_in[5];
    float* out = (float*)d_out;

    const int M = N_NODES;
    const int E = N_EDGES;

    char* p = (char*)d_ws;
    auto alloc = [&](size_t bytes) {
        char* q = p;
        p += (bytes + 255) & ~(size_t)255;
        return q;
    };
    int*            deg  = (int*)alloc(sizeof(int) * N_NODES);
    int*            rptr = (int*)alloc(sizeof(int) * (N_NODES + 1));
    int*            bsum = (int*)alloc(sizeof(int) * 512);
    unsigned short* ke   = (unsigned short*)alloc(sizeof(unsigned short) * N_EDGES); // 6.4 MB
    unsigned*       cvp  = (unsigned*)alloc(sizeof(unsigned) * N_EDGES);             // 12.8 MB
    _Float16*       W1T  = (_Float16*)alloc(sizeof(_Float16) * F_IN * HIDDEN);
    _Float16*       W2T  = (_Float16*)alloc(sizeof(_Float16) * NPAD * HIDDEN);
    unsigned char*  H1   = (unsigned char*)alloc((size_t)N_NODES * HIDDEN);          // 25.6 MB fp8
    _Float16*       H2   = (_Float16*)alloc(sizeof(_Float16) * (size_t)N_NODES * H2STRIDE); // 12.8 MB

    // K1: deg=0 + weight conversions
    init_kernel<<<(F_IN * HIDDEN) / 256, 256, 0, stream>>>(W1, W2, W1T, W2T, deg);

    // K2: histogram + per-edge rank
    hist2_kernel<<<E / 256, 256, 0, stream>>>(erow, deg, ke, E);

    // K3-K5: exclusive scan of deg -> rptr
    scanA_kernel<<<N_SCANB, SCAN_B, 0, stream>>>(deg, rptr, bsum, N_NODES);
    scanB_kernel<<<1, 512, 0, stream>>>(bsum, N_SCANB);
    scanC_kernel<<<N_SCANB, SCAN_B, 0, stream>>>(rptr, bsum, N_NODES, E);

    // K6: merged GEMM1-fp8-out (128x256 tile) || fill (grid-stride x4)
    fill_gemm1_kernel<<<G1_BLOCKS + FILLB, 512, 0, stream>>>(
        x, W1T, H1, M, erow, ecol, evals, rptr, ke, cvp, E);

    // K7: fused layer-1 aggregation (fp8 gather, 24/iter) + relu + @W2
    spmm_gemm2_kernel<<<M / FB_ROWS, 1024, 0, stream>>>(rptr, cvp, H1, W2T, H2);

    // K8: layer-2 aggregation (48/iter) + relu + log_softmax
    spmm40_ls_kernel<<<M / 4, 256, 0, stream>>>(rptr, cvp, H2, out);
}

// Round 21
// 468.017 us; speedup vs baseline: 1.0543x; 1.0543x over previous
//
#include <hip/hip_runtime.h>
#include <math.h>

#define N_NODES 100000
#define N_EDGES 3200000
#define F_IN    512
#define HIDDEN  256
#define NCLASS  40
#define NPAD    48
#define H2STRIDE 64
#define FB_ROWS 16
#define G1_BLOCKS ((N_NODES + 127) / 128)        // 782
#define FILL_BLOCKS5 (N_EDGES / 512)             // 6250

#define SCAN_B  256
#define N_SCANB ((N_NODES + SCAN_B - 1) / SCAN_B)   // 391

typedef __attribute__((ext_vector_type(8))) _Float16 half8;
typedef __attribute__((ext_vector_type(4))) _Float16 half4;
typedef __attribute__((ext_vector_type(4))) float    f32x4;
typedef __attribute__((ext_vector_type(2))) float    f32x2;

__device__ __forceinline__ float unpack_val(unsigned pk) {
    unsigned short hb = (unsigned short)(pk & 0x7FFFu);
    _Float16 h = *(_Float16*)&hb;
    return (float)h;
}

// ---------------------------------------------------------------------------
// init: deg = 0  +  W1 -> W1T [256][512] fp16  +  W2 -> W2T [48][256] fp16
// ---------------------------------------------------------------------------
__global__ __launch_bounds__(256) void init_kernel(const float* __restrict__ W1,
                                                   const float* __restrict__ W2,
                                                   _Float16* __restrict__ W1T,
                                                   _Float16* __restrict__ W2T,
                                                   int* __restrict__ deg) {
    int o = blockIdx.x * 256 + threadIdx.x;   // 0..131071
    {
        int n = o >> 9, k = o & 511;
        W1T[o] = (_Float16)W1[(size_t)k * HIDDEN + n];
    }
    if (o < NPAD * HIDDEN) {                  // 0..12287
        int n = o >> 8, k = o & 255;
        W2T[o] = (n < NCLASS) ? (_Float16)W2[(size_t)k * NCLASS + n] : (_Float16)0.f;
    }
    if (o < N_NODES) deg[o] = 0;
}

// ---------------------------------------------------------------------------
// CSR build: pass 1 = histogram + per-edge rank (atomic return value)
// ---------------------------------------------------------------------------
__global__ __launch_bounds__(256) void hist2_kernel(const int* __restrict__ erow,
                                                    int* __restrict__ deg,
                                                    unsigned short* __restrict__ ke, int E) {
    int e = blockIdx.x * 256 + threadIdx.x;
    if (e < E) ke[e] = (unsigned short)atomicAdd(&deg[erow[e]], 1);
}

__global__ __launch_bounds__(256) void scanA_kernel(const int* __restrict__ deg,
                                                    int* __restrict__ rptr,
                                                    int* __restrict__ bsum, int n) {
    __shared__ int s[SCAN_B];
    int i = blockIdx.x * SCAN_B + threadIdx.x;
    int v = (i < n) ? deg[i] : 0;
    s[threadIdx.x] = v;
    __syncthreads();
    #pragma unroll
    for (int off = 1; off < SCAN_B; off <<= 1) {
        int t = (threadIdx.x >= off) ? s[threadIdx.x - off] : 0;
        __syncthreads();
        s[threadIdx.x] += t;
        __syncthreads();
    }
    if (i < n) rptr[i] = s[threadIdx.x] - v;
    if (threadIdx.x == SCAN_B - 1) bsum[blockIdx.x] = s[SCAN_B - 1];
}

__global__ __launch_bounds__(512) void scanB_kernel(int* __restrict__ bsum, int nb) {
    __shared__ int s[512];
    int t = threadIdx.x;
    int v = (t < nb) ? bsum[t] : 0;
    s[t] = v;
    __syncthreads();
    #pragma unroll
    for (int off = 1; off < 512; off <<= 1) {
        int x = (t >= off) ? s[t - off] : 0;
        __syncthreads();
        s[t] += x;
        __syncthreads();
    }
    if (t < nb) bsum[t] = s[t] - v;
}

__global__ __launch_bounds__(256) void scanC_kernel(int* __restrict__ rptr,
                                                    const int* __restrict__ bsum,
                                                    int n, int E) {
    int i = blockIdx.x * SCAN_B + threadIdx.x;
    if (i < n) rptr[i] += bsum[blockIdx.x];
    if (i == 0) rptr[n] = E;
}

// ---------------------------------------------------------------------------
// MERGED (512 threads): blocks [0, G1_BLOCKS) = GEMM1 ; rest = fill.
// GEMM1: 128x256 tile, 8 waves each with a 64x64 wave tile. (R18-proven)
// ---------------------------------------------------------------------------
__global__ __launch_bounds__(512) void fill_gemm1_kernel(
        const float* __restrict__ A, const _Float16* __restrict__ BT,
        unsigned char* __restrict__ C, int M,
        const int* __restrict__ erow, const int* __restrict__ ecol,
        const float* __restrict__ evals, const int* __restrict__ rptr,
        const unsigned short* __restrict__ ke, unsigned* __restrict__ cvp, int E) {
    __shared__ __align__(16) char smem[30720];

    if (blockIdx.x >= G1_BLOCKS) {
        // ---- fill: permute packed (col,val) -> CSR slots, no atomics ----
        int e = (blockIdx.x - G1_BLOCKS) * 512 + threadIdx.x;
        if (e < E) {
            int p = rptr[erow[e]] + ke[e];
            _Float16 h = (_Float16)evals[e];
            unsigned short hb = *(unsigned short*)&h;
            cvp[p] = ((unsigned)ecol[e] << 15) | (unsigned)(hb & 0x7FFFu);
        }
        return;
    }

    _Float16 (*As)[40]  = (_Float16 (*)[40])smem;               // 128x40 = 10240 B
    _Float16 (*Bs)[40]  = (_Float16 (*)[40])(smem + 10240);     // 256x40 = 20480 B
    _Float16 (*sC)[264] = (_Float16 (*)[264])smem;              //  32x264 = 16896 B (aliases)

    const int t    = threadIdx.x;       // 0..511
    const int m0   = blockIdx.x * 128;
    const int lane = t & 63;
    const int wid  = t >> 6;            // 0..7
    const int wm   = wid >> 2;          // 0..1 (64-row half)
    const int wn   = wid & 3;           // 0..3 (64-col quarter)
    const int lr   = lane & 15, lk = lane >> 4;

    f32x4 acc[4][4] = {};

    const int  ar   = t >> 2;           // 0..127
    const int  aq   = t & 3;            // 0..3 (8-float chunk)
    const bool aval = (m0 + ar) < M;
    const float*    aptr = A  + (size_t)(m0 + ar) * F_IN + aq * 8;
    const _Float16* bptr = BT + (size_t)(t >> 1) * F_IN + (t & 1) * 16;

    float4 a0 = {0.f,0.f,0.f,0.f}, a1 = {0.f,0.f,0.f,0.f};
    half8 b0, b1;
    if (aval) { a0 = *(const float4*)(aptr); a1 = *(const float4*)(aptr + 4); }
    { const half8* bp = (const half8*)(bptr); b0 = bp[0]; b1 = bp[1]; }

    for (int k0 = 0; k0 < F_IN; k0 += 32) {
        half8 ah;
        ah[0]=(_Float16)a0.x; ah[1]=(_Float16)a0.y; ah[2]=(_Float16)a0.z; ah[3]=(_Float16)a0.w;
        ah[4]=(_Float16)a1.x; ah[5]=(_Float16)a1.y; ah[6]=(_Float16)a1.z; ah[7]=(_Float16)a1.w;
        *(half8*)&As[ar][aq * 8] = ah;
        *(half8*)&Bs[t >> 1][(t & 1) * 16]     = b0;
        *(half8*)&Bs[t >> 1][(t & 1) * 16 + 8] = b1;
        __syncthreads();

        if (k0 + 32 < F_IN) {
            if (aval) {
                a0 = *(const float4*)(aptr + k0 + 32);
                a1 = *(const float4*)(aptr + k0 + 36);
            }
            const half8* bp = (const half8*)(bptr + k0 + 32);
            b0 = bp[0]; b1 = bp[1];
        }

        half8 af[4], bf[4];
        #pragma unroll
        for (int fm = 0; fm < 4; fm++) af[fm] = *(half8*)&As[wm * 64 + fm * 16 + lr][lk * 8];
        #pragma unroll
        for (int fn = 0; fn < 4; fn++) bf[fn] = *(half8*)&Bs[wn * 64 + fn * 16 + lr][lk * 8];
        #pragma unroll
        for (int fm = 0; fm < 4; fm++)
            #pragma unroll
            for (int fn = 0; fn < 4; fn++)
                acc[fm][fn] = __builtin_amdgcn_mfma_f32_16x16x32_f16(af[fm], bf[fn], acc[fm][fn], 0, 0, 0);
        __syncthreads();
    }

    // epilogue: four 32-row passes; pass p covers rows [32p, 32p+32)
    #pragma unroll
    for (int pass = 0; pass < 4; pass++) {
        if (wm == (pass >> 1)) {
            #pragma unroll
            for (int f2 = 0; f2 < 2; f2++) {
                int fm = (pass & 1) * 2 + f2;
                #pragma unroll
                for (int fn = 0; fn < 4; fn++)
                    #pragma unroll
                    for (int j = 0; j < 4; j++) {
                        int row = f2 * 16 + lk * 4 + j;        // 0..31
                        int col = wn * 64 + fn * 16 + lr;
                        sC[row][col] = (_Float16)acc[fm][fn][j];
                    }
            }
        }
        __syncthreads();

        int row = t >> 4;          // 0..31
        int c   = t & 15;          // 0..15 (16 fp8 chunk)
        int m   = m0 + pass * 32 + row;
        if (m < M) {
            const half8* sp = (const half8*)&sC[row][c * 16];
            half8 h0 = sp[0], h1 = sp[1];
            unsigned w0 = __builtin_amdgcn_cvt_pk_fp8_f32((float)h0[0], (float)h0[1], 0u, false);
            w0 = __builtin_amdgcn_cvt_pk_fp8_f32((float)h0[2], (float)h0[3], w0, true);
            unsigned w1 = __builtin_amdgcn_cvt_pk_fp8_f32((float)h0[4], (float)h0[5], 0u, false);
            w1 = __builtin_amdgcn_cvt_pk_fp8_f32((float)h0[6], (float)h0[7], w1, true);
            unsigned w2 = __builtin_amdgcn_cvt_pk_fp8_f32((float)h1[0], (float)h1[1], 0u, false);
            w2 = __builtin_amdgcn_cvt_pk_fp8_f32((float)h1[2], (float)h1[3], w2, true);
            unsigned w3 = __builtin_amdgcn_cvt_pk_fp8_f32((float)h1[4], (float)h1[5], 0u, false);
            w3 = __builtin_amdgcn_cvt_pk_fp8_f32((float)h1[6], (float)h1[7], w3, true);
            *(uint4*)(C + (size_t)m * HIDDEN + c * 16) = make_uint4(w0, w1, w2, w3);
        }
        __syncthreads();
    }
}

// ---------------------------------------------------------------------------
// FUSED: SpMM gather D=256 (fp8 table) + ReLU + GEMM2 (@W2 via MFMA epilogue).
// 1024 threads = 16 waves = 16 rows. Software-pipelined: next iteration's 4
// cvp (pk) loads issue during current iteration's H1 gathers + FMAs.
// ---------------------------------------------------------------------------
__global__ __launch_bounds__(1024) void spmm_gemm2_kernel(const int* __restrict__ rptr,
                                                          const unsigned* __restrict__ cvp,
                                                          const unsigned char* __restrict__ H1,
                                                          const _Float16* __restrict__ W2T,
                                                          _Float16* __restrict__ H2) {
    __shared__ _Float16 sW2[NPAD][264];     // 25344 B
    __shared__ _Float16 sRow[16][264];      //  8448 B

    int t = threadIdx.x;
    int wave = t >> 6, lane = t & 63;
    int m0 = blockIdx.x * FB_ROWS;
    int r = m0 + wave;

    // stage W2T (48x256 = 1536 half8 chunks) : 1.5 per thread
    #pragma unroll
    for (int i = 0; i < 2; i++) {
        int idx = t + i * 1024;             // 0..2047
        if (idx < NPAD * 32) {
            int row = idx >> 5, c8 = idx & 31;
            *(half8*)&sW2[row][c8 * 8] = *(const half8*)(W2T + (size_t)row * HIDDEN + c8 * 8);
        }
    }

    int e0 = rptr[r], e1 = rptr[r + 1];
    int qf = lane >> 4;            // which edge of the quad (0..3)
    int fl = lane & 15;            // 16B feature block (16 fp8 each)

    float acc[16] = {};
    unsigned pkb[4];
    if (e0 < e1) {
        #pragma unroll
        for (int u = 0; u < 4; u++) {
            int idx = e0 + 4 * u + qf;
            pkb[u] = cvp[idx < e1 ? idx : (e1 - 1)];
        }
    }
    for (int e = e0; e < e1; e += 16) {
        unsigned pkc[4];
        #pragma unroll
        for (int u = 0; u < 4; u++) pkc[u] = pkb[u];
        // prefetch next iteration's pk block (overlaps with gathers below)
        if (e + 16 < e1) {
            #pragma unroll
            for (int u = 0; u < 4; u++) {
                int idx = e + 16 + 4 * u + qf;
                pkb[u] = cvp[idx < e1 ? idx : (e1 - 1)];
            }
        }
        #pragma unroll
        for (int u = 0; u < 4; u++) {
            int idx = e + 4 * u + qf;
            bool ok = idx < e1;
            unsigned pk = pkc[u];
            float v = ok ? unpack_val(pk) : 0.f;
            int col = (int)(pk >> 15);
            uint4 raw = *(const uint4*)(H1 + (size_t)col * HIDDEN + fl * 16);
            #pragma unroll
            for (int q = 0; q < 4; q++) {
                unsigned wq = (q == 0) ? raw.x : (q == 1) ? raw.y : (q == 2) ? raw.z : raw.w;
                f32x2 lo = __builtin_amdgcn_cvt_pk_f32_fp8(wq, false);
                f32x2 hi = __builtin_amdgcn_cvt_pk_f32_fp8(wq, true);
                acc[q*4 + 0] += v * lo[0];
                acc[q*4 + 1] += v * lo[1];
                acc[q*4 + 2] += v * hi[0];
                acc[q*4 + 3] += v * hi[1];
            }
        }
    }
    // merge the 4 quad groups: lanes 0..15 end with the full sums
    #pragma unroll
    for (int j = 0; j < 16; j++) {
        acc[j] += __shfl_xor(acc[j], 32);
        acc[j] += __shfl_xor(acc[j], 16);
    }

    if (lane < 16) {
        half8 o0, o1;
        #pragma unroll
        for (int j = 0; j < 8; j++) {
            o0[j] = (_Float16)fmaxf(acc[j], 0.f);
            o1[j] = (_Float16)fmaxf(acc[8 + j], 0.f);
        }
        *(half8*)&sRow[wave][fl * 16]     = o0;
        *(half8*)&sRow[wave][fl * 16 + 8] = o1;
    }
    __syncthreads();

    // MFMA epilogue on wave 0: [16x256] @ [48x256]^T
    if (wave == 0) {
        int lr = lane & 15, lk = lane >> 4;
        f32x4 acc2[3] = {};
        #pragma unroll
        for (int ks = 0; ks < 8; ks++) {
            half8 af = *(half8*)&sRow[lr][ks * 32 + lk * 8];
            #pragma unroll
            for (int fn = 0; fn < 3; fn++) {
                half8 bf = *(half8*)&sW2[fn * 16 + lr][ks * 32 + lk * 8];
                acc2[fn] = __builtin_amdgcn_mfma_f32_16x16x32_f16(af, bf, acc2[fn], 0, 0, 0);
            }
        }
        #pragma unroll
        for (int fn = 0; fn < 3; fn++)
            #pragma unroll
            for (int j = 0; j < 4; j++) {
                int row = lk * 4 + j;       // 0..15
                int col = fn * 16 + lr;     // 0..47
                H2[(size_t)(m0 + row) * H2STRIDE + col] = (_Float16)acc2[fn][j];
            }
    }
}

// ---------------------------------------------------------------------------
// SpMM gather D=40 (fp16, stride-64 rows) + ReLU + log_softmax.
// One wave per row; 24 edges/iter; next iteration's pk pair prefetched.
// ---------------------------------------------------------------------------
__global__ __launch_bounds__(256) void spmm40_ls_kernel(const int* __restrict__ rptr,
                                                        const unsigned* __restrict__ cvp,
                                                        const _Float16* __restrict__ H2,
                                                        float* __restrict__ out) {
    int t = threadIdx.x;
    int wave = t >> 6, lane = t & 63;
    int r = blockIdx.x * 4 + wave;

    int e0 = rptr[r], e1 = rptr[r + 1];
    int s = lane / 5;           // edge slot 0..11 (lane 60..63 inactive)
    int g = lane % 5;           // feature block: classes g*8 .. g*8+7
    bool lact = lane < 60;

    float acc[8] = {};
    unsigned pb0 = 0, pb1 = 0;
    if (e0 < e1) {
        int i0 = e0 + s, i1 = e0 + 12 + s;
        pb0 = cvp[(lact && i0 < e1) ? i0 : (e1 - 1)];
        pb1 = cvp[(lact && i1 < e1) ? i1 : (e1 - 1)];
    }
    for (int e = e0; e < e1; e += 24) {
        unsigned pk0 = pb0, pk1 = pb1;
        int en = e + 24;
        if (en < e1) {
            int i0 = en + s, i1 = en + 12 + s;
            pb0 = cvp[(lact && i0 < e1) ? i0 : (e1 - 1)];
            pb1 = cvp[(lact && i1 < e1) ? i1 : (e1 - 1)];
        }
        bool ok0 = lact && (e + s < e1);
        bool ok1 = lact && (e + 12 + s < e1);
        float v0 = ok0 ? unpack_val(pk0) : 0.f;
        float v1 = ok1 ? unpack_val(pk1) : 0.f;
        int c0 = (int)(pk0 >> 15), c1 = (int)(pk1 >> 15);
        half8 h0 = *(const half8*)(H2 + (size_t)c0 * H2STRIDE + g * 8);
        half8 h1 = *(const half8*)(H2 + (size_t)c1 * H2STRIDE + g * 8);
        #pragma unroll
        for (int j = 0; j < 8; j++)
            acc[j] += v0 * (float)h0[j] + v1 * (float)h1[j];
    }

    // slot-tree reduce: 12 -> 6 -> 3 -> 1
    #pragma unroll
    for (int j = 0; j < 8; j++) acc[j] += __shfl(acc[j], lane + 30);
    #pragma unroll
    for (int j = 0; j < 8; j++) acc[j] += __shfl(acc[j], lane + 15);
    #pragma unroll
    for (int j = 0; j < 8; j++) {
        float t1 = __shfl(acc[j], lane + 5);
        float t2 = __shfl(acc[j], lane + 10);
        acc[j] += t1 + t2;
    }

    bool act = lane < 5;
    float z[8];
    float mx = -INFINITY;
    #pragma unroll
    for (int j = 0; j < 8; j++) {
        z[j] = act ? fmaxf(acc[j], 0.f) : -INFINITY;
        mx = fmaxf(mx, z[j]);
    }
    mx = fmaxf(mx, __shfl_xor(mx, 1));
    mx = fmaxf(mx, __shfl_xor(mx, 2));
    mx = fmaxf(mx, __shfl_xor(mx, 4));

    float sm = 0.f;
    #pragma unroll
    for (int j = 0; j < 8; j++)
        sm += act ? expf(z[j] - mx) : 0.f;
    sm += __shfl_xor(sm, 1);
    sm += __shfl_xor(sm, 2);
    sm += __shfl_xor(sm, 4);

    float lse = logf(sm);
    if (act) {
        float4 o0 = {z[0]-mx-lse, z[1]-mx-lse, z[2]-mx-lse, z[3]-mx-lse};
        float4 o1 = {z[4]-mx-lse, z[5]-mx-lse, z[6]-mx-lse, z[7]-mx-lse};
        float4* dp = (float4*)(out + (size_t)r * NCLASS + g * 8);
        dp[0] = o0;
        dp[1] = o1;
    }
}

// ---------------------------------------------------------------------------
extern "C" void kernel_launch(void* const* d_in, const int* in_sizes, int n_in,
                              void* d_out, int out_size, void* d_ws, size_t ws_size,
                              hipStream_t stream) {
    const float* x     = (const float*)d_in[0];
    const int*   erow  = (const int*)d_in[1];
    const int*   ecol  = (const int*)d_in[2];
    const float* evals = (const float*)d_in[3];
    const float* W1    = (const float*)d_in[4];
    const float* W2    = (const float*)d_in[5];
    float* out = (float*)d_out;

    const int M = N_NODES;
    const int E = N_EDGES;

    char* p = (char*)d_ws;
    auto alloc = [&](size_t bytes) {
        char* q = p;
        p += (bytes + 255) & ~(size_t)255;
        return q;
    };
    int*            deg  = (int*)alloc(sizeof(int) * N_NODES);
    int*            rptr = (int*)alloc(sizeof(int) * (N_NODES + 1));
    int*            bsum = (int*)alloc(sizeof(int) * 512);
    unsigned short* ke   = (unsigned short*)alloc(sizeof(unsigned short) * N_EDGES); // 6.4 MB
    unsigned*       cvp  = (unsigned*)alloc(sizeof(unsigned) * N_EDGES);             // 12.8 MB
    _Float16*       W1T  = (_Float16*)alloc(sizeof(_Float16) * F_IN * HIDDEN);
    _Float16*       W2T  = (_Float16*)alloc(sizeof(_Float16) * NPAD * HIDDEN);
    unsigned char*  H1   = (unsigned char*)alloc((size_t)N_NODES * HIDDEN);          // 25.6 MB fp8
    _Float16*       H2   = (_Float16*)alloc(sizeof(_Float16) * (size_t)N_NODES * H2STRIDE); // 12.8 MB

    // K1: deg=0 + weight conversions
    init_kernel<<<(F_IN * HIDDEN) / 256, 256, 0, stream>>>(W1, W2, W1T, W2T, deg);

    // K2: histogram + per-edge rank
    hist2_kernel<<<E / 256, 256, 0, stream>>>(erow, deg, ke, E);

    // K3-K5: exclusive scan of deg -> rptr
    scanA_kernel<<<N_SCANB, SCAN_B, 0, stream>>>(deg, rptr, bsum, N_NODES);
    scanB_kernel<<<1, 512, 0, stream>>>(bsum, N_SCANB);
    scanC_kernel<<<N_SCANB, SCAN_B, 0, stream>>>(rptr, bsum, N_NODES, E);

    // K6: merged GEMM1-fp8-out (128x256 tile, 512-thread blocks 0..781) || fill
    fill_gemm1_kernel<<<G1_BLOCKS + FILL_BLOCKS5, 512, 0, stream>>>(
        x, W1T, H1, M, erow, ecol, evals, rptr, ke, cvp, E);

    // K7: fused layer-1 aggregation (fp8 gather, pk-pipelined) + relu + @W2
    spmm_gemm2_kernel<<<M / FB_ROWS, 1024, 0, stream>>>(rptr, cvp, H1, W2T, H2);

    // K8: layer-2 aggregation (pk-pipelined) + relu + log_softmax
    spmm40_ls_kernel<<<M / 4, 256, 0, stream>>>(rptr, cvp, H2, out);
}